// Round 14
// baseline (301.636 us; speedup 1.0000x reference)
//
#include <hip/hip_runtime.h>
#include <math.h>

#define NB 128
#define NC 320
#define NG 5
#define CPG 64
#define NHID 40

typedef short bf16x8 __attribute__((ext_vector_type(8)));
typedef short s16x4  __attribute__((ext_vector_type(4)));
typedef float f32x4  __attribute__((ext_vector_type(4)));

__device__ __forceinline__ float sigf(float x){ return 1.0f/(1.0f+expf(-x)); }

__device__ __forceinline__ unsigned short f2b(float f){
  unsigned u = __float_as_uint(f);
  unsigned r = (u + 0x7fffu + ((u >> 16) & 1u)) >> 16;
  return (unsigned short)r;
}
__device__ __forceinline__ float b2f(unsigned short u){
  return __uint_as_float(((unsigned)u) << 16);
}

__device__ __forceinline__ void gll16(const void* g, void* l){
  __builtin_amdgcn_global_load_lds(
      (const __attribute__((address_space(1))) void*)g,
      (__attribute__((address_space(3))) void*)l, 16, 0, 0);
}

// ---------------------------------------------------------------------------
// k_prep: one kernel for all precompute.
//   blocks [0,768):   WgT gather — each block recomputes the 256-entry
//                     circular-conv kernel (JAX fp32 mask arithmetic) in LDS,
//                     then writes one 256-wide row of WgT[band][p][:].
//   blocks [768,1728): weight transform OIHW fp32 -> WA[band][tap][cib][cig][co][8j]
// ---------------------------------------------------------------------------
__global__ __launch_bounds__(256) void k_prep(const float* __restrict__ lowc,
                                              const float* __restrict__ highc,
                                              const float* __restrict__ w0,
                                              const float* __restrict__ w1,
                                              const float* __restrict__ w2,
                                              unsigned short* __restrict__ WgT,
                                              unsigned short* __restrict__ WAb){
  __shared__ float msh[256];
  __shared__ float cost[16];
  __shared__ float ksh[256];
  __shared__ float wsh[2880];
  int bid = blockIdx.x, t = threadIdx.x;

  if (bid < 768){
    int band = bid >> 8, p = bid & 255;
    float lc = lowc[0], hc = highc[0];
    {
      int a1 = t >> 4, a2 = t & 15;
      const float step = 2.0f / 15.0f;
      float cy = -1.0f + step * (float)a1;
      float cx = -1.0f + step * (float)a2;
      float dist = sqrtf(cx*cx + cy*cy) / 1.41421356237309515f;
      float m = band == 0 ? sigf((lc - dist) * 1e6f)
              : band == 1 ? sigf((dist - lc) * 1e6f) * sigf((hc - dist) * 1e6f)
                          : sigf((dist - hc) * 1e6f);
      msh[t] = m;
    }
    if (t < 16) cost[t] = cosf((float)t * 0.392699081698724154f);
    __syncthreads();
    {
      int d1 = t >> 4, d2 = t & 15;
      float s = 0.f;
      int ang0 = (8*d1 + 8*d2) & 15;
      for (int a1 = 0; a1 < 16; ++a1){
        int ang = (ang0 + a1*d1) & 15;
        #pragma unroll
        for (int a2 = 0; a2 < 16; ++a2){
          s += msh[a1*16 + a2] * cost[ang];
          ang = (ang + d2) & 15;
        }
      }
      ksh[t] = s * (1.0f/256.0f);
    }
    __syncthreads();
    int d1 = ((p >> 4) - (t >> 4)) & 15;
    int d2 = ((p & 15) - (t & 15)) & 15;
    WgT[(size_t)(band << 16) + (p << 8) + t] = f2b(ksh[(d1 << 4) | d2]);
  } else {
    int bid2 = bid - 768;
    int band = bid2 / 320, co = bid2 % 320;
    const float* w = band == 0 ? w0 : (band == 1 ? w1 : w2);
    const float* src = w + (size_t)co * 2880;
    for (int i = t; i < 2880; i += 256) wsh[i] = src[i];
    __syncthreads();
    unsigned short* dst = WAb + (size_t)band * 921600;
    for (int g = t; g < 360; g += 256){
      int tap = g / 40, r = g % 40;
      unsigned short tmp[8];
      #pragma unroll
      for (int j = 0; j < 8; ++j) tmp[j] = f2b(wsh[(r*8 + j)*9 + tap]);
      s16x4* o = (s16x4*)(dst + (size_t)g * 2560 + co*8);
      o[0] = *(s16x4*)tmp;
      o[1] = *(s16x4*)(tmp + 4);
    }
  }
}

// ---------------------------------------------------------------------------
// Band GEMM, ALL 3 BANDS per block: X staged once into XOR-swizzled bf16 LDS;
// emits avg[b][c]; zeros the halo slots for its ci-quarter (all 3 bands);
// optionally emits xb (bf16 copy of x) for the epilogue's residual read.
// ---------------------------------------------------------------------------
__global__ __launch_bounds__(256, 4) void k_bandg3(const float* __restrict__ x,
                                                   const unsigned short* __restrict__ WgT,
                                                   unsigned short* __restrict__ bandT,
                                                   float* __restrict__ avgOut,
                                                   unsigned short* __restrict__ xbOut){
  __shared__ unsigned short xt[64*256];   // 32 KB
  int tid = threadIdx.x;
  int wgid = (blockIdx.x & 7)*80 + (blockIdx.x >> 3);
  int b = wgid / 5, cq = wgid % 5;
  int cibase = cq * 64;
  size_t rowbase = (size_t)wgid * 64;

  {
    int r = tid >> 2, c0 = (tid & 3) * 64;
    const float* xp = x + (rowbase + r)*256 + c0;
    unsigned short* dp = xt + r*256;
    int sw = (r & 7) << 3;
    float rs = 0.f;
    #pragma unroll
    for (int j = 0; j < 64; j += 4){
      float4 f = *(const float4*)(xp + j);
      rs += f.x + f.y + f.z + f.w;
      unsigned short t4[4] = { f2b(f.x), f2b(f.y), f2b(f.z), f2b(f.w) };
      *(s16x4*)(dp + ((c0 + j) ^ sw)) = *(s16x4*)t4;
      if (xbOut) *(s16x4*)(xbOut + (rowbase + r)*256 + c0 + j) = *(s16x4*)t4;
    }
    rs += __shfl_down(rs, 1);
    rs += __shfl_down(rs, 2);
    if ((tid & 3) == 0) avgOut[rowbase + r] = rs * (1.0f/256.0f);
  }

  // zero halo slots for this (b, ci-quarter) across the 3 bands
  for (int i = tid; i < 3264; i += 256){         // 3 bands * 68 slots * 16 granules
    int band = i / 1088, r = i % 1088;
    int si = r >> 4, cg = r & 15;
    int rr, cc;
    if (si < 18)      { rr = 0;        cc = si;      }
    else if (si < 36) { rr = 17;       cc = si - 18; }
    else if (si < 52) { rr = si - 35;  cc = 0;       }
    else              { rr = si - 51;  cc = 17;      }
    s16x4 z = {0,0,0,0};
    *(s16x4*)(bandT + (size_t)band*13271040 +
              ((size_t)(b*324 + rr*18 + cc))*NC + cibase + cg*4) = z;
  }
  __syncthreads();

  int l  = tid & 63;
  int wq = tid >> 6;
  int cig = l >> 4, lan = l & 15;

  for (int band = 0; band < 3; ++band){
    const unsigned short* Wg = WgT + (size_t)band * 65536;
    unsigned short* bT = bandT + (size_t)band * 13271040;

    f32x4 acc[4][4];
    #pragma unroll
    for (int m = 0; m < 4; ++m)
      #pragma unroll
      for (int n = 0; n < 4; ++n) acc[m][n] = (f32x4){0.f,0.f,0.f,0.f};

    #pragma unroll 2
    for (int ks = 0; ks < 8; ++ks){
      int koff = ks*32 + cig*8;
      bf16x8 a[4], bv[4];
      #pragma unroll
      for (int m = 0; m < 4; ++m){
        int row = m*16 + lan;
        a[m] = *(const bf16x8*)(xt + row*256 + (koff ^ ((row & 7) << 3)));
      }
      #pragma unroll
      for (int n = 0; n < 4; ++n){
        int p = wq*64 + n*16 + lan;
        bv[n] = *(const bf16x8*)(Wg + (size_t)p*256 + koff);
      }
      #pragma unroll
      for (int m = 0; m < 4; ++m)
        #pragma unroll
        for (int n = 0; n < 4; ++n)
          acc[m][n] = __builtin_amdgcn_mfma_f32_16x16x32_bf16(a[m], bv[n], acc[m][n], 0, 0, 0);
    }

    #pragma unroll
    for (int m = 0; m < 4; ++m){
      #pragma unroll
      for (int n = 0; n < 4; ++n){
        int p = wq*64 + n*16 + lan;
        int slot = ((p >> 4) + 1) * 18 + (p & 15) + 1;
        int ci = cibase + m*16 + cig*4;
        unsigned short o[4] = { f2b(acc[m][n][0]), f2b(acc[m][n][1]),
                                f2b(acc[m][n][2]), f2b(acc[m][n][3]) };
        *(s16x4*)(bT + ((size_t)(b*324 + slot))*NC + ci) = *(s16x4*)o;
      }
    }
  }
}

// ---------------------------------------------------------------------------
// Conv3x3 implicit GEMM (round-12 verified best): A (weights) in REGISTERS
// (depth-1 dbuf, per-lane coalesced global loads), B (band) in LDS (2 buffers,
// staged 1/cib via global_load_lds, reused 9 taps). Barriers only at B swaps.
// __launch_bounds__(256, 2): combined VGPR+AGPR ~204 needs the 256 cap.
// Block = 256 thr (4 waves: 2co x 2px), tile 160co x 128px, K=2880.
// Grid 1536 = (band, b, ch, ph), XCD-swizzled.
// ---------------------------------------------------------------------------
__global__ __launch_bounds__(256, 2) void k_convg(const unsigned short* __restrict__ bandT,
                                                  const unsigned short* __restrict__ WAb,
                                                  const float* __restrict__ bias0,
                                                  const float* __restrict__ bias1,
                                                  const float* __restrict__ bias2,
                                                  unsigned short* __restrict__ convb,
                                                  float* __restrict__ stats_part){
  __shared__ char ldsB[2*11520];
  __shared__ float stw[4][5][2];

  int tid = threadIdx.x;
  int wgid = (blockIdx.x & 7)*192 + (blockIdx.x >> 3);   // bijective XCD swizzle
  int band = wgid / 512; int rem = wgid & 511;
  int b = rem >> 2, ch = (rem >> 1) & 1, ph = rem & 1;

  const unsigned short* bT = bandT + (size_t)band*13271040 + (size_t)b*103680;
  const unsigned short* WA = WAb + (size_t)band*921600;
  const float* bias = band == 0 ? bias0 : (band == 1 ? bias1 : bias2);
  unsigned short* cbp = convb + (size_t)band * 10485760;

  int l = tid & 63, w = tid >> 6;
  int wco = w >> 1, wpx = w & 1;
  int cig = l >> 4, lan = l & 15;
  int cobase = ch*160 + wco*80;
  int px0 = ph*128 + wpx*64;

  // A per-lane register-load base (shorts): [tap][cib][cig][co:320][8j]
  const unsigned short* Areg = WA + cig*2560 + ch*1280 + (wco*80 + lan)*8;

  // B staging source offsets (shorts)
  int gb0 = tid, gb1 = tid + 256, gb2 = tid + 512;
  int boff0 = (ph*144 + gb0%180)*320 + (gb0/180)*8;
  int boff1 = (ph*144 + gb1%180)*320 + (gb1/180)*8;
  int boff2 = (ph*144 + gb2%180)*320 + (gb2/180)*8;     // used iff tid<208

  // B LDS read offset (bytes)
  int Bread0 = (cig*180 + (wpx*4 + 1)*18 + lan + 1)*16;  // + dhdw + n*288

  f32x4 acc[5][4];
  #pragma unroll
  for (int m = 0; m < 5; ++m)
    #pragma unroll
    for (int n = 0; n < 4; ++n) acc[m][n] = (f32x4){0.f,0.f,0.f,0.f};

  bf16x8 A0[5], A1[5];

#define LOADA(ARR, OFS) do { \
    const unsigned short* p_ = Areg + (OFS); \
    ARR[0] = *(const bf16x8*)(p_); \
    ARR[1] = *(const bf16x8*)(p_ + 128); \
    ARR[2] = *(const bf16x8*)(p_ + 256); \
    ARR[3] = *(const bf16x8*)(p_ + 384); \
    ARR[4] = *(const bf16x8*)(p_ + 512); \
  } while(0)

#define STAGE_B(CN, BUF) do { \
    const unsigned short* sB = bT + (CN)*32; \
    char* dB = ldsB + (BUF)*11520; \
    gll16(sB + boff0, dB + tid*16); \
    gll16(sB + boff1, dB + 4096 + tid*16); \
    if (tid < 208) gll16(sB + boff2, dB + 8192 + tid*16); \
  } while(0)

  // prologue: B(0)->buf0, A(tap0,cib0)->A0
  STAGE_B(0, 0);
  LOADA(A0, 0);
  asm volatile("s_waitcnt vmcnt(0)" ::: "memory");
  __builtin_amdgcn_s_barrier();

  // 5 body iterations of 18 taps (2 ci-blocks) each; parity compile-time.
#define BODY(T, CURA, NXTA) do { \
    if ((T) == 0){ \
      __builtin_amdgcn_s_barrier(); \
      STAGE_B(cc2 + 1, 1); \
    } else if ((T) == 9){ \
      __builtin_amdgcn_s_barrier(); \
      if (cib2 < 4) STAGE_B(cc2 + 2, 0); \
    } \
    const char* Bb = ldsB + (((T) >= 9) ? 11520 : 0) + Bread0 \
                   + (((((T)%9)/3)*18 + (((T)%9)%3) - 19)*16); \
    bf16x8 b0 = *(const bf16x8*)(Bb); \
    bf16x8 b1 = *(const bf16x8*)(Bb + 288); \
    bf16x8 b2 = *(const bf16x8*)(Bb + 576); \
    bf16x8 b3 = *(const bf16x8*)(Bb + 864); \
    { \
      size_t ofs_ = ((T) == 17) ? (cc + 20480) \
          : ((size_t)(((((T)+1)%9))*102400) + cc + ((((T)+1) >= 9) ? 10240 : 0)); \
      LOADA(NXTA, ofs_); \
    } \
    __builtin_amdgcn_s_setprio(1); \
    acc[0][0]=__builtin_amdgcn_mfma_f32_16x16x32_bf16(CURA[0],b0,acc[0][0],0,0,0); \
    acc[0][1]=__builtin_amdgcn_mfma_f32_16x16x32_bf16(CURA[0],b1,acc[0][1],0,0,0); \
    acc[0][2]=__builtin_amdgcn_mfma_f32_16x16x32_bf16(CURA[0],b2,acc[0][2],0,0,0); \
    acc[0][3]=__builtin_amdgcn_mfma_f32_16x16x32_bf16(CURA[0],b3,acc[0][3],0,0,0); \
    acc[1][0]=__builtin_amdgcn_mfma_f32_16x16x32_bf16(CURA[1],b0,acc[1][0],0,0,0); \
    acc[1][1]=__builtin_amdgcn_mfma_f32_16x16x32_bf16(CURA[1],b1,acc[1][1],0,0,0); \
    acc[1][2]=__builtin_amdgcn_mfma_f32_16x16x32_bf16(CURA[1],b2,acc[1][2],0,0,0); \
    acc[1][3]=__builtin_amdgcn_mfma_f32_16x16x32_bf16(CURA[1],b3,acc[1][3],0,0,0); \
    acc[2][0]=__builtin_amdgcn_mfma_f32_16x16x32_bf16(CURA[2],b0,acc[2][0],0,0,0); \
    acc[2][1]=__builtin_amdgcn_mfma_f32_16x16x32_bf16(CURA[2],b1,acc[2][1],0,0,0); \
    acc[2][2]=__builtin_amdgcn_mfma_f32_16x16x32_bf16(CURA[2],b2,acc[2][2],0,0,0); \
    acc[2][3]=__builtin_amdgcn_mfma_f32_16x16x32_bf16(CURA[2],b3,acc[2][3],0,0,0); \
    acc[3][0]=__builtin_amdgcn_mfma_f32_16x16x32_bf16(CURA[3],b0,acc[3][0],0,0,0); \
    acc[3][1]=__builtin_amdgcn_mfma_f32_16x16x32_bf16(CURA[3],b1,acc[3][1],0,0,0); \
    acc[3][2]=__builtin_amdgcn_mfma_f32_16x16x32_bf16(CURA[3],b2,acc[3][2],0,0,0); \
    acc[3][3]=__builtin_amdgcn_mfma_f32_16x16x32_bf16(CURA[3],b3,acc[3][3],0,0,0); \
    acc[4][0]=__builtin_amdgcn_mfma_f32_16x16x32_bf16(CURA[4],b0,acc[4][0],0,0,0); \
    acc[4][1]=__builtin_amdgcn_mfma_f32_16x16x32_bf16(CURA[4],b1,acc[4][1],0,0,0); \
    acc[4][2]=__builtin_amdgcn_mfma_f32_16x16x32_bf16(CURA[4],b2,acc[4][2],0,0,0); \
    acc[4][3]=__builtin_amdgcn_mfma_f32_16x16x32_bf16(CURA[4],b3,acc[4][3],0,0,0); \
    __builtin_amdgcn_s_setprio(0); \
  } while(0)

  for (int cib2 = 0; cib2 < 5; ++cib2){
    int cc2 = cib2*2;
    size_t cc = (size_t)cib2 * 20480;
    BODY(0,  A0, A1);  BODY(1,  A1, A0);  BODY(2,  A0, A1);
    BODY(3,  A1, A0);  BODY(4,  A0, A1);  BODY(5,  A1, A0);
    BODY(6,  A0, A1);  BODY(7,  A1, A0);  BODY(8,  A0, A1);
    BODY(9,  A1, A0);  BODY(10, A0, A1);  BODY(11, A1, A0);
    BODY(12, A0, A1);  BODY(13, A1, A0);  BODY(14, A0, A1);
    BODY(15, A1, A0);  BODY(16, A0, A1);  BODY(17, A1, A0);
  }
#undef BODY
#undef STAGE_B
#undef LOADA

  // fold bias (GN stats must include it)
  #pragma unroll
  for (int m = 0; m < 5; ++m)
    #pragma unroll
    for (int r = 0; r < 4; ++r){
      float bvs = bias[cobase + m*16 + cig*4 + r];
      #pragma unroll
      for (int n = 0; n < 4; ++n) acc[m][n][r] += bvs;
    }

  // per-wave GN partial sums (deterministic)
  #pragma unroll
  for (int m = 0; m < 5; ++m){
    float s = 0.f, q = 0.f;
    #pragma unroll
    for (int n = 0; n < 4; ++n)
      #pragma unroll
      for (int r = 0; r < 4; ++r){ float v = acc[m][n][r]; s += v; q += v*v; }
    #pragma unroll
    for (int o = 32; o > 0; o >>= 1){ s += __shfl_xor(s, o); q += __shfl_xor(q, o); }
    if (l == 0){ stw[w][m][0] = s; stw[w][m][1] = q; }
  }

  // store bf16 conv output
  #pragma unroll
  for (int m = 0; m < 5; ++m)
    #pragma unroll
    for (int r = 0; r < 4; ++r){
      int co = cobase + m*16 + cig*4 + r;
      unsigned short* op = cbp + ((size_t)(b*NC + co))*256 + px0 + lan;
      #pragma unroll
      for (int n = 0; n < 4; ++n) op[n*16] = f2b(acc[m][n][r]);
    }

  __syncthreads();
  // block covers groups ch*2 + {0,1,2} (group 2 split across ch)
  if (tid < 6){
    int gl = tid >> 1, comp = tid & 1;
    int g = ch*2 + gl;
    float t = 0.f;
    for (int w2 = 0; w2 < 4; ++w2)
      #pragma unroll
      for (int m = 0; m < 5; ++m)
        if (((ch*160 + (w2 >> 1)*80 + m*16) >> 6) == g) t += stw[w2][m][comp];
    stats_part[((size_t)(band*NB + b)*NG + g)*8 + ch*4 + ph*2 + comp] = t;
  }
}

// ---------------------------------------------------------------------------
// Fused epilogue: channel-attention MLP + GN finalize + residual +
// channel-weights + SA + scale. Block = (b, 64-px QUARTER), 512 thr,
// fl = 40 KB -> ~3 blocks/CU (was 80 KB / 1 block). Residual read from
// bf16 xb when available (halves the x read), else f32 x.
// ---------------------------------------------------------------------------
__global__ __launch_bounds__(512) void k_fuse3(const unsigned short* __restrict__ cb0,
                                               const unsigned short* __restrict__ cb1,
                                               const unsigned short* __restrict__ cb2,
                                               const float* __restrict__ x,
                                               const unsigned short* __restrict__ xb,
                                               const float* __restrict__ stats_part,
                                               const float* __restrict__ g0, const float* __restrict__ be0,
                                               const float* __restrict__ g1, const float* __restrict__ be1,
                                               const float* __restrict__ g2, const float* __restrict__ be2,
                                               const float* __restrict__ avg,
                                               const float* __restrict__ caw1,
                                               const float* __restrict__ cab1,
                                               const float* __restrict__ caw2,
                                               const float* __restrict__ cab2,
                                               const float* __restrict__ saw,
                                               const float* __restrict__ sab,
                                               float* __restrict__ out,
                                               int use_xb){
  __shared__ unsigned short fl[NC*64];      // 40 KB
  __shared__ float mu_s[3][NG], rs_s[3][NG], sh[8][64];
  __shared__ float avs[NC], hsh[NHID], cws[3*NC];
  int b = blockIdx.x >> 2, quarter = blockIdx.x & 3;
  int tid = threadIdx.x;

  if (tid < NC) avs[tid] = avg[b*NC + tid];
  else if (tid >= 496 && tid < 511){
    int t2 = tid - 496;
    int band = t2 / 5, g = t2 % 5;
    const float* sp = stats_part + ((size_t)(band*NB + b)*NG + g)*8;
    float s = 0.f, q = 0.f;
    if (g <= 2){ s += sp[0] + sp[2]; q += sp[1] + sp[3]; }
    if (g >= 2){ s += sp[4] + sp[6]; q += sp[5] + sp[7]; }
    float mu = s * (1.f/16384.f);
    float var = q * (1.f/16384.f) - mu*mu;
    mu_s[band][g] = mu; rs_s[band][g] = rsqrtf(var + 1e-5f);
  }
  __syncthreads();
  if (tid < NHID){
    float s = cab1[tid];
    const float* wr = caw1 + tid*NC;
    for (int i = 0; i < NC; ++i) s += wr[i] * avs[i];
    hsh[tid] = fmaxf(s, 0.0f);
  }
  __syncthreads();
  for (int o = tid; o < 3*NC; o += 512){
    float s = cab2[o];
    const float* wr = caw2 + o*NHID;
    #pragma unroll
    for (int i = 0; i < NHID; ++i) s += wr[i] * hsh[i];
    cws[o] = sigf(s);
  }
  __syncthreads();

  int p = tid & 63, cs = tid >> 6;     // 8 ci-stripes x 64 px
  int px = quarter*64 + p;
  float sacc = 0.f;
  if (use_xb){
    for (int ci = cs; ci < NC; ci += 8){
      int g = ci >> 6;
      size_t idx = ((size_t)(b*NC + ci))*256 + px;
      float xv = b2f(xb[idx]);
      float f =
        cws[ci      ] * ((b2f(cb0[idx]) - mu_s[0][g])*rs_s[0][g]*g0[ci] + be0[ci] + xv) +
        cws[320 + ci] * ((b2f(cb1[idx]) - mu_s[1][g])*rs_s[1][g]*g1[ci] + be1[ci] + xv) +
        cws[640 + ci] * ((b2f(cb2[idx]) - mu_s[2][g])*rs_s[2][g]*g2[ci] + be2[ci] + xv);
      fl[ci*64 + p] = f2b(f);
      sacc += f * saw[ci];
    }
  } else {
    for (int ci = cs; ci < NC; ci += 8){
      int g = ci >> 6;
      size_t idx = ((size_t)(b*NC + ci))*256 + px;
      float xv = x[idx];
      float f =
        cws[ci      ] * ((b2f(cb0[idx]) - mu_s[0][g])*rs_s[0][g]*g0[ci] + be0[ci] + xv) +
        cws[320 + ci] * ((b2f(cb1[idx]) - mu_s[1][g])*rs_s[1][g]*g1[ci] + be1[ci] + xv) +
        cws[640 + ci] * ((b2f(cb2[idx]) - mu_s[2][g])*rs_s[2][g]*g2[ci] + be2[ci] + xv);
      fl[ci*64 + p] = f2b(f);
      sacc += f * saw[ci];
    }
  }
  sh[cs][p] = sacc;
  __syncthreads();
  if (tid < 64){
    float s = sh[0][tid] + sh[1][tid] + sh[2][tid] + sh[3][tid]
            + sh[4][tid] + sh[5][tid] + sh[6][tid] + sh[7][tid];
    sh[0][tid] = sigf(s + sab[0]);
  }
  __syncthreads();
  float swv = sh[0][p];
  for (int ci = cs; ci < NC; ci += 8){
    size_t idx = ((size_t)(b*NC + ci))*256 + px;
    out[idx] = b2f(fl[ci*64 + p]) * swv;
  }
}

extern "C" void kernel_launch(void* const* d_in, const int* in_sizes, int n_in,
                              void* d_out, int out_size, void* d_ws, size_t ws_size,
                              hipStream_t stream){
  (void)in_sizes; (void)n_in; (void)out_size;
  const float* x     = (const float*)d_in[0];
  const float* lowc  = (const float*)d_in[1];
  const float* highc = (const float*)d_in[2];
  const float* ca_w1 = (const float*)d_in[3];
  const float* ca_b1 = (const float*)d_in[4];
  const float* ca_w2 = (const float*)d_in[5];
  const float* ca_b2 = (const float*)d_in[6];
  const float* conv_w[3] = {(const float*)d_in[7],  (const float*)d_in[11], (const float*)d_in[15]};
  const float* conv_b[3] = {(const float*)d_in[8],  (const float*)d_in[12], (const float*)d_in[16]};
  const float* gn_g[3]   = {(const float*)d_in[9],  (const float*)d_in[13], (const float*)d_in[17]};
  const float* gn_be[3]  = {(const float*)d_in[10], (const float*)d_in[14], (const float*)d_in[18]};
  const float* sa_w = (const float*)d_in[19];
  const float* sa_b = (const float*)d_in[20];
  float* out = (float*)d_out;

  char* base = (char*)d_ws;
  unsigned short* WgT   = (unsigned short*)(base + 4096);      // 393216
  unsigned short* WAb   = (unsigned short*)(base + 397312);    // 5529600 -> 5926912
  unsigned short* bandT = (unsigned short*)(base + 5926912);   // 3 x 26542080 = 79626240
  unsigned short* cbb   = (unsigned short*)(base + 85553152);  // 3 x 20971520 = 62914560
  float*          avg   = (float*)(base + 148959232);          // 163840
  float*          stats = (float*)(base + 149123072);          // 61440 -> 149184512
  unsigned short* xbuf  = (unsigned short*)(base + 149184512); // 20971520 -> 170156032
  int use_xb = (ws_size >= (size_t)170156032) ? 1 : 0;
  unsigned short* cb0 = cbb;
  unsigned short* cb1 = cbb + 10485760;
  unsigned short* cb2 = cbb + 20971520;

  k_prep  <<<1728, 256, 0, stream>>>(lowc, highc, conv_w[0], conv_w[1], conv_w[2],
                                     WgT, WAb);

  k_bandg3<<<640, 256, 0, stream>>>(x, WgT, bandT, avg, use_xb ? xbuf : nullptr);

  k_convg<<<1536, 256, 0, stream>>>(bandT, WAb, conv_b[0], conv_b[1], conv_b[2],
                                    cbb, stats);

  k_fuse3<<<512, 512, 0, stream>>>(cb0, cb1, cb2, x, xbuf, stats,
                                   gn_g[0], gn_be[0], gn_g[1], gn_be[1], gn_g[2], gn_be[2],
                                   avg, ca_w1, ca_b1, ca_w2, ca_b2,
                                   sa_w, sa_b, out, use_xb);
}

// Round 15
// 262.623 us; speedup vs baseline: 1.1486x; 1.1486x over previous
//
#include <hip/hip_runtime.h>
#include <math.h>

#define NB 128
#define NC 320
#define NG 5
#define CPG 64
#define NHID 40

typedef short bf16x8 __attribute__((ext_vector_type(8)));
typedef short s16x4  __attribute__((ext_vector_type(4)));
typedef float f32x4  __attribute__((ext_vector_type(4)));

__device__ __forceinline__ float sigf(float x){ return 1.0f/(1.0f+expf(-x)); }

__device__ __forceinline__ unsigned short f2b(float f){
  unsigned u = __float_as_uint(f);
  unsigned r = (u + 0x7fffu + ((u >> 16) & 1u)) >> 16;
  return (unsigned short)r;
}
__device__ __forceinline__ float b2f(unsigned short u){
  return __uint_as_float(((unsigned)u) << 16);
}

__device__ __forceinline__ void gll16(const void* g, void* l){
  __builtin_amdgcn_global_load_lds(
      (const __attribute__((address_space(1))) void*)g,
      (__attribute__((address_space(3))) void*)l, 16, 0, 0);
}

// ---------------------------------------------------------------------------
// k_prep: one kernel for all precompute.
//   blocks [0,768):   WgT gather — each block recomputes the 256-entry
//                     circular-conv kernel (JAX fp32 mask arithmetic) in LDS,
//                     then writes one 256-wide row of WgT[band][p][:].
//   blocks [768,1728): weight transform OIHW fp32 -> WA[band][tap][cib][cig][co][8j]
// ---------------------------------------------------------------------------
__global__ __launch_bounds__(256) void k_prep(const float* __restrict__ lowc,
                                              const float* __restrict__ highc,
                                              const float* __restrict__ w0,
                                              const float* __restrict__ w1,
                                              const float* __restrict__ w2,
                                              unsigned short* __restrict__ WgT,
                                              unsigned short* __restrict__ WAb){
  __shared__ float msh[256];
  __shared__ float cost[16];
  __shared__ float ksh[256];
  __shared__ float wsh[2880];
  int bid = blockIdx.x, t = threadIdx.x;

  if (bid < 768){
    int band = bid >> 8, p = bid & 255;
    float lc = lowc[0], hc = highc[0];
    {
      int a1 = t >> 4, a2 = t & 15;
      const float step = 2.0f / 15.0f;
      float cy = -1.0f + step * (float)a1;
      float cx = -1.0f + step * (float)a2;
      float dist = sqrtf(cx*cx + cy*cy) / 1.41421356237309515f;
      float m = band == 0 ? sigf((lc - dist) * 1e6f)
              : band == 1 ? sigf((dist - lc) * 1e6f) * sigf((hc - dist) * 1e6f)
                          : sigf((dist - hc) * 1e6f);
      msh[t] = m;
    }
    if (t < 16) cost[t] = cosf((float)t * 0.392699081698724154f);
    __syncthreads();
    {
      int d1 = t >> 4, d2 = t & 15;
      float s = 0.f;
      int ang0 = (8*d1 + 8*d2) & 15;
      for (int a1 = 0; a1 < 16; ++a1){
        int ang = (ang0 + a1*d1) & 15;
        #pragma unroll
        for (int a2 = 0; a2 < 16; ++a2){
          s += msh[a1*16 + a2] * cost[ang];
          ang = (ang + d2) & 15;
        }
      }
      ksh[t] = s * (1.0f/256.0f);
    }
    __syncthreads();
    int d1 = ((p >> 4) - (t >> 4)) & 15;
    int d2 = ((p & 15) - (t & 15)) & 15;
    WgT[(size_t)(band << 16) + (p << 8) + t] = f2b(ksh[(d1 << 4) | d2]);
  } else {
    int bid2 = bid - 768;
    int band = bid2 / 320, co = bid2 % 320;
    const float* w = band == 0 ? w0 : (band == 1 ? w1 : w2);
    const float* src = w + (size_t)co * 2880;
    for (int i = t; i < 2880; i += 256) wsh[i] = src[i];
    __syncthreads();
    unsigned short* dst = WAb + (size_t)band * 921600;
    for (int g = t; g < 360; g += 256){
      int tap = g / 40, r = g % 40;
      unsigned short tmp[8];
      #pragma unroll
      for (int j = 0; j < 8; ++j) tmp[j] = f2b(wsh[(r*8 + j)*9 + tap]);
      s16x4* o = (s16x4*)(dst + (size_t)g * 2560 + co*8);
      o[0] = *(s16x4*)tmp;
      o[1] = *(s16x4*)(tmp + 4);
    }
  }
}

// ---------------------------------------------------------------------------
// Band GEMM, ALL 3 BANDS per block: X staged once into XOR-swizzled bf16 LDS;
// emits avg[b][c]; zeros the halo slots for its ci-quarter (all 3 bands).
// ---------------------------------------------------------------------------
__global__ __launch_bounds__(256, 4) void k_bandg3(const float* __restrict__ x,
                                                   const unsigned short* __restrict__ WgT,
                                                   unsigned short* __restrict__ bandT,
                                                   float* __restrict__ avgOut){
  __shared__ unsigned short xt[64*256];   // 32 KB
  int tid = threadIdx.x;
  int wgid = (blockIdx.x & 7)*80 + (blockIdx.x >> 3);
  int b = wgid / 5, cq = wgid % 5;
  int cibase = cq * 64;
  size_t rowbase = (size_t)wgid * 64;

  {
    int r = tid >> 2, c0 = (tid & 3) * 64;
    const float* xp = x + (rowbase + r)*256 + c0;
    unsigned short* dp = xt + r*256;
    int sw = (r & 7) << 3;
    float rs = 0.f;
    #pragma unroll
    for (int j = 0; j < 64; j += 4){
      float4 f = *(const float4*)(xp + j);
      rs += f.x + f.y + f.z + f.w;
      unsigned short t4[4] = { f2b(f.x), f2b(f.y), f2b(f.z), f2b(f.w) };
      *(s16x4*)(dp + ((c0 + j) ^ sw)) = *(s16x4*)t4;
    }
    rs += __shfl_down(rs, 1);
    rs += __shfl_down(rs, 2);
    if ((tid & 3) == 0) avgOut[rowbase + r] = rs * (1.0f/256.0f);
  }

  // zero halo slots for this (b, ci-quarter) across the 3 bands
  for (int i = tid; i < 3264; i += 256){         // 3 bands * 68 slots * 16 granules
    int band = i / 1088, r = i % 1088;
    int si = r >> 4, cg = r & 15;
    int rr, cc;
    if (si < 18)      { rr = 0;        cc = si;      }
    else if (si < 36) { rr = 17;       cc = si - 18; }
    else if (si < 52) { rr = si - 35;  cc = 0;       }
    else              { rr = si - 51;  cc = 17;      }
    s16x4 z = {0,0,0,0};
    *(s16x4*)(bandT + (size_t)band*13271040 +
              ((size_t)(b*324 + rr*18 + cc))*NC + cibase + cg*4) = z;
  }
  __syncthreads();

  int l  = tid & 63;
  int wq = tid >> 6;
  int cig = l >> 4, lan = l & 15;

  for (int band = 0; band < 3; ++band){
    const unsigned short* Wg = WgT + (size_t)band * 65536;
    unsigned short* bT = bandT + (size_t)band * 13271040;

    f32x4 acc[4][4];
    #pragma unroll
    for (int m = 0; m < 4; ++m)
      #pragma unroll
      for (int n = 0; n < 4; ++n) acc[m][n] = (f32x4){0.f,0.f,0.f,0.f};

    #pragma unroll 2
    for (int ks = 0; ks < 8; ++ks){
      int koff = ks*32 + cig*8;
      bf16x8 a[4], bv[4];
      #pragma unroll
      for (int m = 0; m < 4; ++m){
        int row = m*16 + lan;
        a[m] = *(const bf16x8*)(xt + row*256 + (koff ^ ((row & 7) << 3)));
      }
      #pragma unroll
      for (int n = 0; n < 4; ++n){
        int p = wq*64 + n*16 + lan;
        bv[n] = *(const bf16x8*)(Wg + (size_t)p*256 + koff);
      }
      #pragma unroll
      for (int m = 0; m < 4; ++m)
        #pragma unroll
        for (int n = 0; n < 4; ++n)
          acc[m][n] = __builtin_amdgcn_mfma_f32_16x16x32_bf16(a[m], bv[n], acc[m][n], 0, 0, 0);
    }

    #pragma unroll
    for (int m = 0; m < 4; ++m){
      #pragma unroll
      for (int n = 0; n < 4; ++n){
        int p = wq*64 + n*16 + lan;
        int slot = ((p >> 4) + 1) * 18 + (p & 15) + 1;
        int ci = cibase + m*16 + cig*4;
        unsigned short o[4] = { f2b(acc[m][n][0]), f2b(acc[m][n][1]),
                                f2b(acc[m][n][2]), f2b(acc[m][n][3]) };
        *(s16x4*)(bT + ((size_t)(b*324 + slot))*NC + ci) = *(s16x4*)o;
      }
    }
  }
}

// ---------------------------------------------------------------------------
// Conv3x3 implicit GEMM: A (weights) in REGISTERS, now TRIPLE-buffered
// (prefetch A(T+2) at tap T -> two MFMA clusters of latency cover for the
// L2 A-loads; depth-1 left ~100-300 cyc unhidden each tap). B (band) in LDS
// (2 buffers, staged 1/cib via global_load_lds, reused 9 taps). Barriers only
// at B swaps. 18-tap unrolled body: 18%3==0 keeps buffer parity compile-time.
// __launch_bounds__(256, 2): ~140 VGPR + 80 AGPR = 220 < 256 cap.
// Block = 256 thr (4 waves: 2co x 2px), tile 160co x 128px, K=2880.
// Grid 1536 = (band, b, ch, ph), XCD-swizzled.
// ---------------------------------------------------------------------------
__global__ __launch_bounds__(256, 2) void k_convg(const unsigned short* __restrict__ bandT,
                                                  const unsigned short* __restrict__ WAb,
                                                  const float* __restrict__ bias0,
                                                  const float* __restrict__ bias1,
                                                  const float* __restrict__ bias2,
                                                  unsigned short* __restrict__ convb,
                                                  float* __restrict__ stats_part){
  __shared__ char ldsB[2*11520];
  __shared__ float stw[4][5][2];

  int tid = threadIdx.x;
  int wgid = (blockIdx.x & 7)*192 + (blockIdx.x >> 3);   // bijective XCD swizzle
  int band = wgid / 512; int rem = wgid & 511;
  int b = rem >> 2, ch = (rem >> 1) & 1, ph = rem & 1;

  const unsigned short* bT = bandT + (size_t)band*13271040 + (size_t)b*103680;
  const unsigned short* WA = WAb + (size_t)band*921600;
  const float* bias = band == 0 ? bias0 : (band == 1 ? bias1 : bias2);
  unsigned short* cbp = convb + (size_t)band * 10485760;

  int l = tid & 63, w = tid >> 6;
  int wco = w >> 1, wpx = w & 1;
  int cig = l >> 4, lan = l & 15;
  int cobase = ch*160 + wco*80;
  int px0 = ph*128 + wpx*64;

  // A per-lane register-load base (shorts): [tap][cib][cig][co:320][8j]
  const unsigned short* Areg = WA + cig*2560 + ch*1280 + (wco*80 + lan)*8;

  // B staging source offsets (shorts)
  int gb0 = tid, gb1 = tid + 256, gb2 = tid + 512;
  int boff0 = (ph*144 + gb0%180)*320 + (gb0/180)*8;
  int boff1 = (ph*144 + gb1%180)*320 + (gb1/180)*8;
  int boff2 = (ph*144 + gb2%180)*320 + (gb2/180)*8;     // used iff tid<208

  // B LDS read offset (bytes)
  int Bread0 = (cig*180 + (wpx*4 + 1)*18 + lan + 1)*16;  // + dhdw + n*288

  f32x4 acc[5][4];
  #pragma unroll
  for (int m = 0; m < 5; ++m)
    #pragma unroll
    for (int n = 0; n < 4; ++n) acc[m][n] = (f32x4){0.f,0.f,0.f,0.f};

  bf16x8 Aa[5], Ab[5], Ac[5];

#define LOADA(ARR, OFS) do { \
    const unsigned short* p_ = Areg + (OFS); \
    ARR[0] = *(const bf16x8*)(p_); \
    ARR[1] = *(const bf16x8*)(p_ + 128); \
    ARR[2] = *(const bf16x8*)(p_ + 256); \
    ARR[3] = *(const bf16x8*)(p_ + 384); \
    ARR[4] = *(const bf16x8*)(p_ + 512); \
  } while(0)

#define STAGE_B(CN, BUF) do { \
    const unsigned short* sB = bT + (CN)*32; \
    char* dB = ldsB + (BUF)*11520; \
    gll16(sB + boff0, dB + tid*16); \
    gll16(sB + boff1, dB + 4096 + tid*16); \
    if (tid < 208) gll16(sB + boff2, dB + 8192 + tid*16); \
  } while(0)

  // prologue: B(0)->buf0, A(0)->Aa, A(1)->Ab
  STAGE_B(0, 0);
  LOADA(Aa, 0);
  LOADA(Ab, 102400);
  asm volatile("s_waitcnt vmcnt(0)" ::: "memory");
  __builtin_amdgcn_s_barrier();

  // 5 body iterations of 18 taps (2 ci-blocks) each; parity compile-time.
  // A(T+2) offset: T+2<=8 -> (T+2)*102400 + cc ; 9..17 -> (T+2-9)*102400+cc+10240 ;
  // 18 -> cc+20480 ; 19 -> 102400+cc+20480. Skip loads past K end (last body).
#define BODY(T, CURA, LD2A) do { \
    if ((T) == 0){ \
      __builtin_amdgcn_s_barrier(); \
      STAGE_B(cc2 + 1, 1); \
    } else if ((T) == 9){ \
      __builtin_amdgcn_s_barrier(); \
      if (cib2 < 4) STAGE_B(cc2 + 2, 0); \
    } \
    const char* Bb = ldsB + (((T) >= 9) ? 11520 : 0) + Bread0 \
                   + (((((T)%9)/3)*18 + (((T)%9)%3) - 19)*16); \
    bf16x8 b0 = *(const bf16x8*)(Bb); \
    bf16x8 b1 = *(const bf16x8*)(Bb + 288); \
    bf16x8 b2 = *(const bf16x8*)(Bb + 576); \
    bf16x8 b3 = *(const bf16x8*)(Bb + 864); \
    if (cib2 < 4 || (T) < 16){ \
      size_t ofs_; \
      if ((T) + 2 <= 8)       ofs_ = (size_t)(((T)+2)*102400) + cc; \
      else if ((T) + 2 <= 17) ofs_ = (size_t)(((T)-7)*102400) + cc + 10240; \
      else if ((T) + 2 == 18) ofs_ = cc + 20480; \
      else                    ofs_ = (size_t)102400 + cc + 20480; \
      LOADA(LD2A, ofs_); \
    } \
    __builtin_amdgcn_s_setprio(1); \
    acc[0][0]=__builtin_amdgcn_mfma_f32_16x16x32_bf16(CURA[0],b0,acc[0][0],0,0,0); \
    acc[0][1]=__builtin_amdgcn_mfma_f32_16x16x32_bf16(CURA[0],b1,acc[0][1],0,0,0); \
    acc[0][2]=__builtin_amdgcn_mfma_f32_16x16x32_bf16(CURA[0],b2,acc[0][2],0,0,0); \
    acc[0][3]=__builtin_amdgcn_mfma_f32_16x16x32_bf16(CURA[0],b3,acc[0][3],0,0,0); \
    acc[1][0]=__builtin_amdgcn_mfma_f32_16x16x32_bf16(CURA[1],b0,acc[1][0],0,0,0); \
    acc[1][1]=__builtin_amdgcn_mfma_f32_16x16x32_bf16(CURA[1],b1,acc[1][1],0,0,0); \
    acc[1][2]=__builtin_amdgcn_mfma_f32_16x16x32_bf16(CURA[1],b2,acc[1][2],0,0,0); \
    acc[1][3]=__builtin_amdgcn_mfma_f32_16x16x32_bf16(CURA[1],b3,acc[1][3],0,0,0); \
    acc[2][0]=__builtin_amdgcn_mfma_f32_16x16x32_bf16(CURA[2],b0,acc[2][0],0,0,0); \
    acc[2][1]=__builtin_amdgcn_mfma_f32_16x16x32_bf16(CURA[2],b1,acc[2][1],0,0,0); \
    acc[2][2]=__builtin_amdgcn_mfma_f32_16x16x32_bf16(CURA[2],b2,acc[2][2],0,0,0); \
    acc[2][3]=__builtin_amdgcn_mfma_f32_16x16x32_bf16(CURA[2],b3,acc[2][3],0,0,0); \
    acc[3][0]=__builtin_amdgcn_mfma_f32_16x16x32_bf16(CURA[3],b0,acc[3][0],0,0,0); \
    acc[3][1]=__builtin_amdgcn_mfma_f32_16x16x32_bf16(CURA[3],b1,acc[3][1],0,0,0); \
    acc[3][2]=__builtin_amdgcn_mfma_f32_16x16x32_bf16(CURA[3],b2,acc[3][2],0,0,0); \
    acc[3][3]=__builtin_amdgcn_mfma_f32_16x16x32_bf16(CURA[3],b3,acc[3][3],0,0,0); \
    acc[4][0]=__builtin_amdgcn_mfma_f32_16x16x32_bf16(CURA[4],b0,acc[4][0],0,0,0); \
    acc[4][1]=__builtin_amdgcn_mfma_f32_16x16x32_bf16(CURA[4],b1,acc[4][1],0,0,0); \
    acc[4][2]=__builtin_amdgcn_mfma_f32_16x16x32_bf16(CURA[4],b2,acc[4][2],0,0,0); \
    acc[4][3]=__builtin_amdgcn_mfma_f32_16x16x32_bf16(CURA[4],b3,acc[4][3],0,0,0); \
    __builtin_amdgcn_s_setprio(0); \
  } while(0)

  for (int cib2 = 0; cib2 < 5; ++cib2){
    int cc2 = cib2*2;
    size_t cc = (size_t)cib2 * 20480;
    BODY(0,  Aa, Ac);  BODY(1,  Ab, Aa);  BODY(2,  Ac, Ab);
    BODY(3,  Aa, Ac);  BODY(4,  Ab, Aa);  BODY(5,  Ac, Ab);
    BODY(6,  Aa, Ac);  BODY(7,  Ab, Aa);  BODY(8,  Ac, Ab);
    BODY(9,  Aa, Ac);  BODY(10, Ab, Aa);  BODY(11, Ac, Ab);
    BODY(12, Aa, Ac);  BODY(13, Ab, Aa);  BODY(14, Ac, Ab);
    BODY(15, Aa, Ac);  BODY(16, Ab, Aa);  BODY(17, Ac, Ab);
  }
#undef BODY
#undef STAGE_B
#undef LOADA

  // fold bias (GN stats must include it)
  #pragma unroll
  for (int m = 0; m < 5; ++m)
    #pragma unroll
    for (int r = 0; r < 4; ++r){
      float bvs = bias[cobase + m*16 + cig*4 + r];
      #pragma unroll
      for (int n = 0; n < 4; ++n) acc[m][n][r] += bvs;
    }

  // per-wave GN partial sums (deterministic)
  #pragma unroll
  for (int m = 0; m < 5; ++m){
    float s = 0.f, q = 0.f;
    #pragma unroll
    for (int n = 0; n < 4; ++n)
      #pragma unroll
      for (int r = 0; r < 4; ++r){ float v = acc[m][n][r]; s += v; q += v*v; }
    #pragma unroll
    for (int o = 32; o > 0; o >>= 1){ s += __shfl_xor(s, o); q += __shfl_xor(q, o); }
    if (l == 0){ stw[w][m][0] = s; stw[w][m][1] = q; }
  }

  // store bf16 conv output
  #pragma unroll
  for (int m = 0; m < 5; ++m)
    #pragma unroll
    for (int r = 0; r < 4; ++r){
      int co = cobase + m*16 + cig*4 + r;
      unsigned short* op = cbp + ((size_t)(b*NC + co))*256 + px0 + lan;
      #pragma unroll
      for (int n = 0; n < 4; ++n) op[n*16] = f2b(acc[m][n][r]);
    }

  __syncthreads();
  // block covers groups ch*2 + {0,1,2} (group 2 split across ch)
  if (tid < 6){
    int gl = tid >> 1, comp = tid & 1;
    int g = ch*2 + gl;
    float t = 0.f;
    for (int w2 = 0; w2 < 4; ++w2)
      #pragma unroll
      for (int m = 0; m < 5; ++m)
        if (((ch*160 + (w2 >> 1)*80 + m*16) >> 6) == g) t += stw[w2][m][comp];
    stats_part[((size_t)(band*NB + b)*NG + g)*8 + ch*4 + ph*2 + comp] = t;
  }
}

// ---------------------------------------------------------------------------
// Fused epilogue (single pass): channel-attention MLP (from avg) + GN finalize
// + residual + channel-weights + SA + scale. Block = (b, 128-px half).
// ---------------------------------------------------------------------------
__global__ __launch_bounds__(512) void k_fuse3(const unsigned short* __restrict__ cb0,
                                               const unsigned short* __restrict__ cb1,
                                               const unsigned short* __restrict__ cb2,
                                               const float* __restrict__ x,
                                               const float* __restrict__ stats_part,
                                               const float* __restrict__ g0, const float* __restrict__ be0,
                                               const float* __restrict__ g1, const float* __restrict__ be1,
                                               const float* __restrict__ g2, const float* __restrict__ be2,
                                               const float* __restrict__ avg,
                                               const float* __restrict__ caw1,
                                               const float* __restrict__ cab1,
                                               const float* __restrict__ caw2,
                                               const float* __restrict__ cab2,
                                               const float* __restrict__ saw,
                                               const float* __restrict__ sab,
                                               float* __restrict__ out){
  __shared__ unsigned short fl[NC*128];     // 80 KB
  __shared__ float mu_s[3][NG], rs_s[3][NG], sh[4][128];
  __shared__ float avs[NC], hsh[NHID], cws[3*NC];
  int b = blockIdx.x >> 1, half = blockIdx.x & 1;
  int tid = threadIdx.x;

  if (tid < NC) avs[tid] = avg[b*NC + tid];
  else if (tid >= 496 && tid < 511){
    int t2 = tid - 496;
    int band = t2 / 5, g = t2 % 5;
    const float* sp = stats_part + ((size_t)(band*NB + b)*NG + g)*8;
    float s = 0.f, q = 0.f;
    if (g <= 2){ s += sp[0] + sp[2]; q += sp[1] + sp[3]; }
    if (g >= 2){ s += sp[4] + sp[6]; q += sp[5] + sp[7]; }
    float mu = s * (1.f/16384.f);
    float var = q * (1.f/16384.f) - mu*mu;
    mu_s[band][g] = mu; rs_s[band][g] = rsqrtf(var + 1e-5f);
  }
  __syncthreads();
  if (tid < NHID){
    float s = cab1[tid];
    const float* wr = caw1 + tid*NC;
    for (int i = 0; i < NC; ++i) s += wr[i] * avs[i];
    hsh[tid] = fmaxf(s, 0.0f);
  }
  __syncthreads();
  for (int o = tid; o < 3*NC; o += 512){
    float s = cab2[o];
    const float* wr = caw2 + o*NHID;
    #pragma unroll
    for (int i = 0; i < NHID; ++i) s += wr[i] * hsh[i];
    cws[o] = sigf(s);
  }
  __syncthreads();

  int p = tid & 127, cs = tid >> 7;
  int px = half*128 + p;
  float sacc = 0.f;
  for (int ci = cs; ci < NC; ci += 4){
    int g = ci >> 6;
    size_t idx = ((size_t)(b*NC + ci))*256 + px;
    float xv = x[idx];
    float f =
      cws[ci      ] * ((b2f(cb0[idx]) - mu_s[0][g])*rs_s[0][g]*g0[ci] + be0[ci] + xv) +
      cws[320 + ci] * ((b2f(cb1[idx]) - mu_s[1][g])*rs_s[1][g]*g1[ci] + be1[ci] + xv) +
      cws[640 + ci] * ((b2f(cb2[idx]) - mu_s[2][g])*rs_s[2][g]*g2[ci] + be2[ci] + xv);
    fl[ci*128 + p] = f2b(f);
    sacc += f * saw[ci];
  }
  sh[cs][p] = sacc;
  __syncthreads();
  if (tid < 128) sh[0][tid] = sigf(sh[0][tid] + sh[1][tid] + sh[2][tid] + sh[3][tid] + sab[0]);
  __syncthreads();
  float swv = sh[0][p];
  for (int ci = cs; ci < NC; ci += 4){
    size_t idx = ((size_t)(b*NC + ci))*256 + px;
    out[idx] = b2f(fl[ci*128 + p]) * swv;
  }
}

extern "C" void kernel_launch(void* const* d_in, const int* in_sizes, int n_in,
                              void* d_out, int out_size, void* d_ws, size_t ws_size,
                              hipStream_t stream){
  (void)in_sizes; (void)n_in; (void)out_size; (void)ws_size;
  const float* x     = (const float*)d_in[0];
  const float* lowc  = (const float*)d_in[1];
  const float* highc = (const float*)d_in[2];
  const float* ca_w1 = (const float*)d_in[3];
  const float* ca_b1 = (const float*)d_in[4];
  const float* ca_w2 = (const float*)d_in[5];
  const float* ca_b2 = (const float*)d_in[6];
  const float* conv_w[3] = {(const float*)d_in[7],  (const float*)d_in[11], (const float*)d_in[15]};
  const float* conv_b[3] = {(const float*)d_in[8],  (const float*)d_in[12], (const float*)d_in[16]};
  const float* gn_g[3]   = {(const float*)d_in[9],  (const float*)d_in[13], (const float*)d_in[17]};
  const float* gn_be[3]  = {(const float*)d_in[10], (const float*)d_in[14], (const float*)d_in[18]};
  const float* sa_w = (const float*)d_in[19];
  const float* sa_b = (const float*)d_in[20];
  float* out = (float*)d_out;

  char* base = (char*)d_ws;
  unsigned short* WgT   = (unsigned short*)(base + 4096);      // 393216
  unsigned short* WAb   = (unsigned short*)(base + 397312);    // 5529600 -> 5926912
  unsigned short* bandT = (unsigned short*)(base + 5926912);   // 3 x 26542080 = 79626240
  unsigned short* cbb   = (unsigned short*)(base + 85553152);  // 3 x 20971520 = 62914560
  float*          avg   = (float*)(base + 148959232);          // 163840
  float*          stats = (float*)(base + 149123072);          // 61440 -> 149184512
  unsigned short* cb0 = cbb;
  unsigned short* cb1 = cbb + 10485760;
  unsigned short* cb2 = cbb + 20971520;

  k_prep  <<<1728, 256, 0, stream>>>(lowc, highc, conv_w[0], conv_w[1], conv_w[2],
                                     WgT, WAb);

  k_bandg3<<<640, 256, 0, stream>>>(x, WgT, bandT, avg);

  k_convg<<<1536, 256, 0, stream>>>(bandT, WAb, conv_b[0], conv_b[1], conv_b[2],
                                    cbb, stats);

  k_fuse3<<<256, 512, 0, stream>>>(cb0, cb1, cb2, x, stats,
                                   gn_g[0], gn_be[0], gn_g[1], gn_be[1], gn_g[2], gn_be[2],
                                   avg, ca_w1, ca_b1, ca_w2, ca_b2,
                                   sa_w, sa_b, out);
}

// Round 16
// 254.866 us; speedup vs baseline: 1.1835x; 1.0304x over previous
//
#include <hip/hip_runtime.h>
#include <math.h>

#define NB 128
#define NC 320
#define NG 5
#define CPG 64
#define NHID 40

typedef short bf16x8 __attribute__((ext_vector_type(8)));
typedef short s16x4  __attribute__((ext_vector_type(4)));
typedef float f32x4  __attribute__((ext_vector_type(4)));

__device__ __forceinline__ float sigf(float x){ return 1.0f/(1.0f+expf(-x)); }

__device__ __forceinline__ unsigned short f2b(float f){
  unsigned u = __float_as_uint(f);
  unsigned r = (u + 0x7fffu + ((u >> 16) & 1u)) >> 16;
  return (unsigned short)r;
}
__device__ __forceinline__ float b2f(unsigned short u){
  return __uint_as_float(((unsigned)u) << 16);
}

__device__ __forceinline__ void gll16(const void* g, void* l){
  __builtin_amdgcn_global_load_lds(
      (const __attribute__((address_space(1))) void*)g,
      (__attribute__((address_space(3))) void*)l, 16, 0, 0);
}

// ---------------------------------------------------------------------------
// k_prep: one kernel for all precompute.
//   blocks [0,768):   WgT gather — each block recomputes the 256-entry
//                     circular-conv kernel (JAX fp32 mask arithmetic) in LDS,
//                     then writes one 256-wide row of WgT[band][p][:].
//   blocks [768,1728): weight transform OIHW fp32 -> WA[band][tap][cib][cig][co][8j]
// ---------------------------------------------------------------------------
__global__ __launch_bounds__(256) void k_prep(const float* __restrict__ lowc,
                                              const float* __restrict__ highc,
                                              const float* __restrict__ w0,
                                              const float* __restrict__ w1,
                                              const float* __restrict__ w2,
                                              unsigned short* __restrict__ WgT,
                                              unsigned short* __restrict__ WAb){
  __shared__ float msh[256];
  __shared__ float cost[16];
  __shared__ float ksh[256];
  __shared__ float wsh[2880];
  int bid = blockIdx.x, t = threadIdx.x;

  if (bid < 768){
    int band = bid >> 8, p = bid & 255;
    float lc = lowc[0], hc = highc[0];
    {
      int a1 = t >> 4, a2 = t & 15;
      const float step = 2.0f / 15.0f;
      float cy = -1.0f + step * (float)a1;
      float cx = -1.0f + step * (float)a2;
      float dist = sqrtf(cx*cx + cy*cy) / 1.41421356237309515f;
      float m = band == 0 ? sigf((lc - dist) * 1e6f)
              : band == 1 ? sigf((dist - lc) * 1e6f) * sigf((hc - dist) * 1e6f)
                          : sigf((dist - hc) * 1e6f);
      msh[t] = m;
    }
    if (t < 16) cost[t] = cosf((float)t * 0.392699081698724154f);
    __syncthreads();
    {
      int d1 = t >> 4, d2 = t & 15;
      float s = 0.f;
      int ang0 = (8*d1 + 8*d2) & 15;
      for (int a1 = 0; a1 < 16; ++a1){
        int ang = (ang0 + a1*d1) & 15;
        #pragma unroll
        for (int a2 = 0; a2 < 16; ++a2){
          s += msh[a1*16 + a2] * cost[ang];
          ang = (ang + d2) & 15;
        }
      }
      ksh[t] = s * (1.0f/256.0f);
    }
    __syncthreads();
    int d1 = ((p >> 4) - (t >> 4)) & 15;
    int d2 = ((p & 15) - (t & 15)) & 15;
    WgT[(size_t)(band << 16) + (p << 8) + t] = f2b(ksh[(d1 << 4) | d2]);
  } else {
    int bid2 = bid - 768;
    int band = bid2 / 320, co = bid2 % 320;
    const float* w = band == 0 ? w0 : (band == 1 ? w1 : w2);
    const float* src = w + (size_t)co * 2880;
    for (int i = t; i < 2880; i += 256) wsh[i] = src[i];
    __syncthreads();
    unsigned short* dst = WAb + (size_t)band * 921600;
    for (int g = t; g < 360; g += 256){
      int tap = g / 40, r = g % 40;
      unsigned short tmp[8];
      #pragma unroll
      for (int j = 0; j < 8; ++j) tmp[j] = f2b(wsh[(r*8 + j)*9 + tap]);
      s16x4* o = (s16x4*)(dst + (size_t)g * 2560 + co*8);
      o[0] = *(s16x4*)tmp;
      o[1] = *(s16x4*)(tmp + 4);
    }
  }
}

// ---------------------------------------------------------------------------
// Band GEMM, ALL 3 BANDS per block: X staged once into XOR-swizzled bf16 LDS;
// emits avg[b][c]; zeros the halo slots for its ci-quarter (all 3 bands).
// ---------------------------------------------------------------------------
__global__ __launch_bounds__(256, 4) void k_bandg3(const float* __restrict__ x,
                                                   const unsigned short* __restrict__ WgT,
                                                   unsigned short* __restrict__ bandT,
                                                   float* __restrict__ avgOut){
  __shared__ unsigned short xt[64*256];   // 32 KB
  int tid = threadIdx.x;
  int wgid = (blockIdx.x & 7)*80 + (blockIdx.x >> 3);
  int b = wgid / 5, cq = wgid % 5;
  int cibase = cq * 64;
  size_t rowbase = (size_t)wgid * 64;

  {
    int r = tid >> 2, c0 = (tid & 3) * 64;
    const float* xp = x + (rowbase + r)*256 + c0;
    unsigned short* dp = xt + r*256;
    int sw = (r & 7) << 3;
    float rs = 0.f;
    #pragma unroll
    for (int j = 0; j < 64; j += 4){
      float4 f = *(const float4*)(xp + j);
      rs += f.x + f.y + f.z + f.w;
      unsigned short t4[4] = { f2b(f.x), f2b(f.y), f2b(f.z), f2b(f.w) };
      *(s16x4*)(dp + ((c0 + j) ^ sw)) = *(s16x4*)t4;
    }
    rs += __shfl_down(rs, 1);
    rs += __shfl_down(rs, 2);
    if ((tid & 3) == 0) avgOut[rowbase + r] = rs * (1.0f/256.0f);
  }

  // zero halo slots for this (b, ci-quarter) across the 3 bands
  for (int i = tid; i < 3264; i += 256){         // 3 bands * 68 slots * 16 granules
    int band = i / 1088, r = i % 1088;
    int si = r >> 4, cg = r & 15;
    int rr, cc;
    if (si < 18)      { rr = 0;        cc = si;      }
    else if (si < 36) { rr = 17;       cc = si - 18; }
    else if (si < 52) { rr = si - 35;  cc = 0;       }
    else              { rr = si - 51;  cc = 17;      }
    s16x4 z = {0,0,0,0};
    *(s16x4*)(bandT + (size_t)band*13271040 +
              ((size_t)(b*324 + rr*18 + cc))*NC + cibase + cg*4) = z;
  }
  __syncthreads();

  int l  = tid & 63;
  int wq = tid >> 6;
  int cig = l >> 4, lan = l & 15;

  for (int band = 0; band < 3; ++band){
    const unsigned short* Wg = WgT + (size_t)band * 65536;
    unsigned short* bT = bandT + (size_t)band * 13271040;

    f32x4 acc[4][4];
    #pragma unroll
    for (int m = 0; m < 4; ++m)
      #pragma unroll
      for (int n = 0; n < 4; ++n) acc[m][n] = (f32x4){0.f,0.f,0.f,0.f};

    #pragma unroll 2
    for (int ks = 0; ks < 8; ++ks){
      int koff = ks*32 + cig*8;
      bf16x8 a[4], bv[4];
      #pragma unroll
      for (int m = 0; m < 4; ++m){
        int row = m*16 + lan;
        a[m] = *(const bf16x8*)(xt + row*256 + (koff ^ ((row & 7) << 3)));
      }
      #pragma unroll
      for (int n = 0; n < 4; ++n){
        int p = wq*64 + n*16 + lan;
        bv[n] = *(const bf16x8*)(Wg + (size_t)p*256 + koff);
      }
      #pragma unroll
      for (int m = 0; m < 4; ++m)
        #pragma unroll
        for (int n = 0; n < 4; ++n)
          acc[m][n] = __builtin_amdgcn_mfma_f32_16x16x32_bf16(a[m], bv[n], acc[m][n], 0, 0, 0);
    }

    #pragma unroll
    for (int m = 0; m < 4; ++m){
      #pragma unroll
      for (int n = 0; n < 4; ++n){
        int p = wq*64 + n*16 + lan;
        int slot = ((p >> 4) + 1) * 18 + (p & 15) + 1;
        int ci = cibase + m*16 + cig*4;
        unsigned short o[4] = { f2b(acc[m][n][0]), f2b(acc[m][n][1]),
                                f2b(acc[m][n][2]), f2b(acc[m][n][3]) };
        *(s16x4*)(bT + ((size_t)(b*324 + slot))*NC + ci) = *(s16x4*)o;
      }
    }
  }
}

// channel-attention MLP per batch: cws[b][band*320+c] (hoisted out of fuse3)
__global__ __launch_bounds__(256) void k_ca(const float* __restrict__ avg,
                                            const float* __restrict__ w1,
                                            const float* __restrict__ b1,
                                            const float* __restrict__ w2,
                                            const float* __restrict__ b2,
                                            float* __restrict__ cw){
  __shared__ float a[NC];
  __shared__ float h[NHID];
  int b = blockIdx.x, t = threadIdx.x;
  a[t] = avg[b * NC + t];
  if (t < NC - 256) a[256 + t] = avg[b * NC + 256 + t];
  __syncthreads();
  if (t < NHID){
    float s = b1[t];
    for (int i = 0; i < NC; ++i) s += w1[t * NC + i] * a[i];
    h[t] = fmaxf(s, 0.0f);
  }
  __syncthreads();
  for (int o = t; o < 3 * NC; o += 256){
    float s = b2[o];
    for (int i = 0; i < NHID; ++i) s += w2[o * NHID + i] * h[i];
    cw[b * (3 * NC) + o] = sigf(s);
  }
}

// ---------------------------------------------------------------------------
// Conv3x3 implicit GEMM (round-12 verified best, banked): A (weights) in
// REGISTERS (depth-1 dbuf — depth-2 measured neutral, r15), B (band) in LDS
// (2 buffers, staged 1/cib via global_load_lds, reused 9 taps). Barriers only
// at B swaps. __launch_bounds__(256, 2): ~100 VGPR + 80 AGPR needs 256 cap
// ((256,3)'s 170 cap spills — r11: WRITE 141 MB).
// Block = 256 thr (4 waves: 2co x 2px), tile 160co x 128px, K=2880.
// Grid 1536 = (band, b, ch, ph), XCD-swizzled.
// ---------------------------------------------------------------------------
__global__ __launch_bounds__(256, 2) void k_convg(const unsigned short* __restrict__ bandT,
                                                  const unsigned short* __restrict__ WAb,
                                                  const float* __restrict__ bias0,
                                                  const float* __restrict__ bias1,
                                                  const float* __restrict__ bias2,
                                                  unsigned short* __restrict__ convb,
                                                  float* __restrict__ stats_part){
  __shared__ char ldsB[2*11520];
  __shared__ float stw[4][5][2];

  int tid = threadIdx.x;
  int wgid = (blockIdx.x & 7)*192 + (blockIdx.x >> 3);   // bijective XCD swizzle
  int band = wgid / 512; int rem = wgid & 511;
  int b = rem >> 2, ch = (rem >> 1) & 1, ph = rem & 1;

  const unsigned short* bT = bandT + (size_t)band*13271040 + (size_t)b*103680;
  const unsigned short* WA = WAb + (size_t)band*921600;
  const float* bias = band == 0 ? bias0 : (band == 1 ? bias1 : bias2);
  unsigned short* cbp = convb + (size_t)band * 10485760;

  int l = tid & 63, w = tid >> 6;
  int wco = w >> 1, wpx = w & 1;
  int cig = l >> 4, lan = l & 15;
  int cobase = ch*160 + wco*80;
  int px0 = ph*128 + wpx*64;

  // A per-lane register-load base (shorts): [tap][cib][cig][co:320][8j]
  const unsigned short* Areg = WA + cig*2560 + ch*1280 + (wco*80 + lan)*8;

  // B staging source offsets (shorts)
  int gb0 = tid, gb1 = tid + 256, gb2 = tid + 512;
  int boff0 = (ph*144 + gb0%180)*320 + (gb0/180)*8;
  int boff1 = (ph*144 + gb1%180)*320 + (gb1/180)*8;
  int boff2 = (ph*144 + gb2%180)*320 + (gb2/180)*8;     // used iff tid<208

  // B LDS read offset (bytes)
  int Bread0 = (cig*180 + (wpx*4 + 1)*18 + lan + 1)*16;  // + dhdw + n*288

  f32x4 acc[5][4];
  #pragma unroll
  for (int m = 0; m < 5; ++m)
    #pragma unroll
    for (int n = 0; n < 4; ++n) acc[m][n] = (f32x4){0.f,0.f,0.f,0.f};

  bf16x8 A0[5], A1[5];

#define LOADA(ARR, OFS) do { \
    const unsigned short* p_ = Areg + (OFS); \
    ARR[0] = *(const bf16x8*)(p_); \
    ARR[1] = *(const bf16x8*)(p_ + 128); \
    ARR[2] = *(const bf16x8*)(p_ + 256); \
    ARR[3] = *(const bf16x8*)(p_ + 384); \
    ARR[4] = *(const bf16x8*)(p_ + 512); \
  } while(0)

#define STAGE_B(CN, BUF) do { \
    const unsigned short* sB = bT + (CN)*32; \
    char* dB = ldsB + (BUF)*11520; \
    gll16(sB + boff0, dB + tid*16); \
    gll16(sB + boff1, dB + 4096 + tid*16); \
    if (tid < 208) gll16(sB + boff2, dB + 8192 + tid*16); \
  } while(0)

  // prologue: B(0)->buf0, A(tap0,cib0)->A0
  STAGE_B(0, 0);
  LOADA(A0, 0);
  asm volatile("s_waitcnt vmcnt(0)" ::: "memory");
  __builtin_amdgcn_s_barrier();

  // 5 body iterations of 18 taps (2 ci-blocks) each; parity compile-time.
#define BODY(T, CURA, NXTA) do { \
    if ((T) == 0){ \
      __builtin_amdgcn_s_barrier(); \
      STAGE_B(cc2 + 1, 1); \
    } else if ((T) == 9){ \
      __builtin_amdgcn_s_barrier(); \
      if (cib2 < 4) STAGE_B(cc2 + 2, 0); \
    } \
    const char* Bb = ldsB + (((T) >= 9) ? 11520 : 0) + Bread0 \
                   + (((((T)%9)/3)*18 + (((T)%9)%3) - 19)*16); \
    bf16x8 b0 = *(const bf16x8*)(Bb); \
    bf16x8 b1 = *(const bf16x8*)(Bb + 288); \
    bf16x8 b2 = *(const bf16x8*)(Bb + 576); \
    bf16x8 b3 = *(const bf16x8*)(Bb + 864); \
    { \
      size_t ofs_ = ((T) == 17) ? (cc + 20480) \
          : ((size_t)(((((T)+1)%9))*102400) + cc + ((((T)+1) >= 9) ? 10240 : 0)); \
      LOADA(NXTA, ofs_); \
    } \
    __builtin_amdgcn_s_setprio(1); \
    acc[0][0]=__builtin_amdgcn_mfma_f32_16x16x32_bf16(CURA[0],b0,acc[0][0],0,0,0); \
    acc[0][1]=__builtin_amdgcn_mfma_f32_16x16x32_bf16(CURA[0],b1,acc[0][1],0,0,0); \
    acc[0][2]=__builtin_amdgcn_mfma_f32_16x16x32_bf16(CURA[0],b2,acc[0][2],0,0,0); \
    acc[0][3]=__builtin_amdgcn_mfma_f32_16x16x32_bf16(CURA[0],b3,acc[0][3],0,0,0); \
    acc[1][0]=__builtin_amdgcn_mfma_f32_16x16x32_bf16(CURA[1],b0,acc[1][0],0,0,0); \
    acc[1][1]=__builtin_amdgcn_mfma_f32_16x16x32_bf16(CURA[1],b1,acc[1][1],0,0,0); \
    acc[1][2]=__builtin_amdgcn_mfma_f32_16x16x32_bf16(CURA[1],b2,acc[1][2],0,0,0); \
    acc[1][3]=__builtin_amdgcn_mfma_f32_16x16x32_bf16(CURA[1],b3,acc[1][3],0,0,0); \
    acc[2][0]=__builtin_amdgcn_mfma_f32_16x16x32_bf16(CURA[2],b0,acc[2][0],0,0,0); \
    acc[2][1]=__builtin_amdgcn_mfma_f32_16x16x32_bf16(CURA[2],b1,acc[2][1],0,0,0); \
    acc[2][2]=__builtin_amdgcn_mfma_f32_16x16x32_bf16(CURA[2],b2,acc[2][2],0,0,0); \
    acc[2][3]=__builtin_amdgcn_mfma_f32_16x16x32_bf16(CURA[2],b3,acc[2][3],0,0,0); \
    acc[3][0]=__builtin_amdgcn_mfma_f32_16x16x32_bf16(CURA[3],b0,acc[3][0],0,0,0); \
    acc[3][1]=__builtin_amdgcn_mfma_f32_16x16x32_bf16(CURA[3],b1,acc[3][1],0,0,0); \
    acc[3][2]=__builtin_amdgcn_mfma_f32_16x16x32_bf16(CURA[3],b2,acc[3][2],0,0,0); \
    acc[3][3]=__builtin_amdgcn_mfma_f32_16x16x32_bf16(CURA[3],b3,acc[3][3],0,0,0); \
    acc[4][0]=__builtin_amdgcn_mfma_f32_16x16x32_bf16(CURA[4],b0,acc[4][0],0,0,0); \
    acc[4][1]=__builtin_amdgcn_mfma_f32_16x16x32_bf16(CURA[4],b1,acc[4][1],0,0,0); \
    acc[4][2]=__builtin_amdgcn_mfma_f32_16x16x32_bf16(CURA[4],b2,acc[4][2],0,0,0); \
    acc[4][3]=__builtin_amdgcn_mfma_f32_16x16x32_bf16(CURA[4],b3,acc[4][3],0,0,0); \
    __builtin_amdgcn_s_setprio(0); \
  } while(0)

  for (int cib2 = 0; cib2 < 5; ++cib2){
    int cc2 = cib2*2;
    size_t cc = (size_t)cib2 * 20480;
    BODY(0,  A0, A1);  BODY(1,  A1, A0);  BODY(2,  A0, A1);
    BODY(3,  A1, A0);  BODY(4,  A0, A1);  BODY(5,  A1, A0);
    BODY(6,  A0, A1);  BODY(7,  A1, A0);  BODY(8,  A0, A1);
    BODY(9,  A1, A0);  BODY(10, A0, A1);  BODY(11, A1, A0);
    BODY(12, A0, A1);  BODY(13, A1, A0);  BODY(14, A0, A1);
    BODY(15, A1, A0);  BODY(16, A0, A1);  BODY(17, A1, A0);
  }
#undef BODY
#undef STAGE_B
#undef LOADA

  // fold bias (GN stats must include it)
  #pragma unroll
  for (int m = 0; m < 5; ++m)
    #pragma unroll
    for (int r = 0; r < 4; ++r){
      float bvs = bias[cobase + m*16 + cig*4 + r];
      #pragma unroll
      for (int n = 0; n < 4; ++n) acc[m][n][r] += bvs;
    }

  // per-wave GN partial sums (deterministic)
  #pragma unroll
  for (int m = 0; m < 5; ++m){
    float s = 0.f, q = 0.f;
    #pragma unroll
    for (int n = 0; n < 4; ++n)
      #pragma unroll
      for (int r = 0; r < 4; ++r){ float v = acc[m][n][r]; s += v; q += v*v; }
    #pragma unroll
    for (int o = 32; o > 0; o >>= 1){ s += __shfl_xor(s, o); q += __shfl_xor(q, o); }
    if (l == 0){ stw[w][m][0] = s; stw[w][m][1] = q; }
  }

  // store bf16 conv output
  #pragma unroll
  for (int m = 0; m < 5; ++m)
    #pragma unroll
    for (int r = 0; r < 4; ++r){
      int co = cobase + m*16 + cig*4 + r;
      unsigned short* op = cbp + ((size_t)(b*NC + co))*256 + px0 + lan;
      #pragma unroll
      for (int n = 0; n < 4; ++n) op[n*16] = f2b(acc[m][n][r]);
    }

  __syncthreads();
  // block covers groups ch*2 + {0,1,2} (group 2 split across ch)
  if (tid < 6){
    int gl = tid >> 1, comp = tid & 1;
    int g = ch*2 + gl;
    float t = 0.f;
    for (int w2 = 0; w2 < 4; ++w2)
      #pragma unroll
      for (int m = 0; m < 5; ++m)
        if (((ch*160 + (w2 >> 1)*80 + m*16) >> 6) == g) t += stw[w2][m][comp];
    stats_part[((size_t)(band*NB + b)*NG + g)*8 + ch*4 + ph*2 + comp] = t;
  }
}

// ---------------------------------------------------------------------------
// Fused epilogue: GN finalize + residual + channel-weights (precomputed cws)
// + SA + scale. Block = (b, 64-px quarter), 512 thr, fl = 40 KB -> ~3 blk/CU.
// ---------------------------------------------------------------------------
__global__ __launch_bounds__(512) void k_fuse3(const unsigned short* __restrict__ cb0,
                                               const unsigned short* __restrict__ cb1,
                                               const unsigned short* __restrict__ cb2,
                                               const float* __restrict__ x,
                                               const float* __restrict__ stats_part,
                                               const float* __restrict__ g0, const float* __restrict__ be0,
                                               const float* __restrict__ g1, const float* __restrict__ be1,
                                               const float* __restrict__ g2, const float* __restrict__ be2,
                                               const float* __restrict__ cw,
                                               const float* __restrict__ saw,
                                               const float* __restrict__ sab,
                                               float* __restrict__ out){
  __shared__ unsigned short fl[NC*64];      // 40 KB
  __shared__ float mu_s[3][NG], rs_s[3][NG], sh[8][64];
  int b = blockIdx.x >> 2, quarter = blockIdx.x & 3;
  int tid = threadIdx.x;
  if (tid < 15){
    int band = tid / 5, g = tid % 5;
    const float* sp = stats_part + ((size_t)(band*NB + b)*NG + g)*8;
    float s = 0.f, q = 0.f;
    if (g <= 2){ s += sp[0] + sp[2]; q += sp[1] + sp[3]; }
    if (g >= 2){ s += sp[4] + sp[6]; q += sp[5] + sp[7]; }
    float mu = s * (1.f/16384.f);
    float var = q * (1.f/16384.f) - mu*mu;
    mu_s[band][g] = mu; rs_s[band][g] = rsqrtf(var + 1e-5f);
  }
  __syncthreads();

  int p = tid & 63, cs = tid >> 6;     // 8 ci-stripes x 64 px
  int px = quarter*64 + p;
  float sacc = 0.f;
  const float* cwb = cw + b*960;
  for (int ci = cs; ci < NC; ci += 8){
    int g = ci >> 6;
    size_t idx = ((size_t)(b*NC + ci))*256 + px;
    float xv = x[idx];
    float f =
      cwb[ci      ] * ((b2f(cb0[idx]) - mu_s[0][g])*rs_s[0][g]*g0[ci] + be0[ci] + xv) +
      cwb[320 + ci] * ((b2f(cb1[idx]) - mu_s[1][g])*rs_s[1][g]*g1[ci] + be1[ci] + xv) +
      cwb[640 + ci] * ((b2f(cb2[idx]) - mu_s[2][g])*rs_s[2][g]*g2[ci] + be2[ci] + xv);
    fl[ci*64 + p] = f2b(f);
    sacc += f * saw[ci];
  }
  sh[cs][p] = sacc;
  __syncthreads();
  if (tid < 64){
    float s = sh[0][tid] + sh[1][tid] + sh[2][tid] + sh[3][tid]
            + sh[4][tid] + sh[5][tid] + sh[6][tid] + sh[7][tid];
    sh[0][tid] = sigf(s + sab[0]);
  }
  __syncthreads();
  float swv = sh[0][p];
  for (int ci = cs; ci < NC; ci += 8){
    size_t idx = ((size_t)(b*NC + ci))*256 + px;
    out[idx] = b2f(fl[ci*64 + p]) * swv;
  }
}

extern "C" void kernel_launch(void* const* d_in, const int* in_sizes, int n_in,
                              void* d_out, int out_size, void* d_ws, size_t ws_size,
                              hipStream_t stream){
  (void)in_sizes; (void)n_in; (void)out_size; (void)ws_size;
  const float* x     = (const float*)d_in[0];
  const float* lowc  = (const float*)d_in[1];
  const float* highc = (const float*)d_in[2];
  const float* ca_w1 = (const float*)d_in[3];
  const float* ca_b1 = (const float*)d_in[4];
  const float* ca_w2 = (const float*)d_in[5];
  const float* ca_b2 = (const float*)d_in[6];
  const float* conv_w[3] = {(const float*)d_in[7],  (const float*)d_in[11], (const float*)d_in[15]};
  const float* conv_b[3] = {(const float*)d_in[8],  (const float*)d_in[12], (const float*)d_in[16]};
  const float* gn_g[3]   = {(const float*)d_in[9],  (const float*)d_in[13], (const float*)d_in[17]};
  const float* gn_be[3]  = {(const float*)d_in[10], (const float*)d_in[14], (const float*)d_in[18]};
  const float* sa_w = (const float*)d_in[19];
  const float* sa_b = (const float*)d_in[20];
  float* out = (float*)d_out;

  char* base = (char*)d_ws;
  unsigned short* WgT   = (unsigned short*)(base + 4096);      // 393216
  unsigned short* WAb   = (unsigned short*)(base + 397312);    // 5529600 -> 5926912
  unsigned short* bandT = (unsigned short*)(base + 5926912);   // 3 x 26542080 = 79626240
  unsigned short* cbb   = (unsigned short*)(base + 85553152);  // 3 x 20971520 = 62914560
  float*          avg   = (float*)(base + 148959232);          // 163840
  float*          stats = (float*)(base + 149123072);          // 61440
  float*          cw    = (float*)(base + 149184512);          // 491520 -> 149676032
  unsigned short* cb0 = cbb;
  unsigned short* cb1 = cbb + 10485760;
  unsigned short* cb2 = cbb + 20971520;

  k_prep  <<<1728, 256, 0, stream>>>(lowc, highc, conv_w[0], conv_w[1], conv_w[2],
                                     WgT, WAb);

  k_bandg3<<<640, 256, 0, stream>>>(x, WgT, bandT, avg);
  k_ca    <<<NB,  256, 0, stream>>>(avg, ca_w1, ca_b1, ca_w2, ca_b2, cw);

  k_convg<<<1536, 256, 0, stream>>>(bandT, WAb, conv_b[0], conv_b[1], conv_b[2],
                                    cbb, stats);

  k_fuse3<<<512, 512, 0, stream>>>(cb0, cb1, cb2, x, stats,
                                   gn_g[0], gn_be[0], gn_g[1], gn_be[1], gn_g[2], gn_be[2],
                                   cw, sa_w, sa_b, out);
}